// Round 1
// baseline (120.348 us; speedup 1.0000x reference)
//
#include <hip/hip_runtime.h>
#include <math.h>

// Shapes: S=4 B=8 N=2048 K=16 D=32 H=128
#define SBN 65536   // S*B*N rows
#define NSB 2048    // N per (s,b)

#if __has_builtin(__builtin_amdgcn_exp2f)
#define EXP2F(x) __builtin_amdgcn_exp2f(x)
#else
#define EXP2F(x) exp2f(x)
#endif
#if __has_builtin(__builtin_amdgcn_rcpf)
#define RCPF(x) __builtin_amdgcn_rcpf(x)
#else
#define RCPF(x) (1.0f / (x))
#endif

__device__ __constant__ float kC = 2.8853900817779268f;   // 2*log2(e)

// ---------------------------------------------------------------------------
// Kernel A: hk'[(sb*16+k)*128 + h] = c * (mu@Wm + tau@Wt + b1)   (512x128 out)
// ---------------------------------------------------------------------------
__global__ __launch_bounds__(256) void hk_kernel(
    const float* __restrict__ mu, const float* __restrict__ tau,
    const float* __restrict__ W1, const float* __restrict__ b1,
    float* __restrict__ hk) {
  int g = blockIdx.x * 256 + threadIdx.x;   // 0..65535
  int h = g & 127;
  int row = g >> 7;                          // 0..511 == sb*16+k
  const float* mur  = mu  + row * 32;
  const float* taur = tau + row * 32;
  float acc = b1[h];
#pragma unroll
  for (int d = 0; d < 32; ++d) {
    acc = fmaf(mur[d],  W1[(32 + d) * 128 + h], acc);   // Wm = W1[32:64]
    acc = fmaf(taur[d], W1[(64 + d) * 128 + h], acc);   // Wt = W1[64:96]
  }
  hk[g] = 2.8853900817779268f * acc;
}

// ---------------------------------------------------------------------------
// Kernel H: hx'[n*128 + h] = c * (x[n,:] @ Wx)   (65536x128 out, Wx=W1[:32])
// One wave per 32 n-rows. Wx columns (h = lane, lane+64) live in VGPRs;
// x row is wave-uniform -> scalar loads.
// ---------------------------------------------------------------------------
__global__ __launch_bounds__(256) void hx_kernel(
    const float* __restrict__ x, const float* __restrict__ W1,
    float* __restrict__ hx) {
  int lane = threadIdx.x & 63;
  int wid = blockIdx.x * 4 + (threadIdx.x >> 6);
  wid = __builtin_amdgcn_readfirstlane(wid);   // force SGPR: n is uniform
  const float c = 2.8853900817779268f;
  float wxa[32], wxb[32];
#pragma unroll
  for (int d = 0; d < 32; ++d) {
    wxa[d] = c * W1[d * 128 + lane];
    wxb[d] = c * W1[d * 128 + 64 + lane];
  }
  int n0 = wid * 32;
  for (int i = 0; i < 32; ++i) {
    int n = n0 + i;
    const float* xr = x + (size_t)n * 32;      // uniform address -> s_load
    float acc_a = 0.f, acc_b = 0.f;
#pragma unroll
    for (int d = 0; d < 32; ++d) {
      float xv = xr[d];
      acc_a = fmaf(xv, wxa[d], acc_a);
      acc_b = fmaf(xv, wxb[d], acc_b);
    }
    hx[(size_t)n * 128 + lane]      = acc_a;
    hx[(size_t)n * 128 + 64 + lane] = acc_b;
  }
}

// ---------------------------------------------------------------------------
// Kernel B: gamma[n,k] = sum_h (-2*W2[h]) * rcp(1 + exp2(hx'[n,h]+hk'[k,h]))
//           (== tanh sum minus a k-uniform const, which softmax cancels)
//           then softmax over k (16-lane shuffle groups).
// Block: 32 n-rows of one (s,b). Thread t: k = t&15, rows nl=t>>4 and nl+16.
// ---------------------------------------------------------------------------
__global__ __launch_bounds__(256) void main_kernel(
    const float* __restrict__ hx, const float* __restrict__ hk,
    const float* __restrict__ W2, float* __restrict__ out) {
  __shared__ __align__(16) float sHx[32][132];   // 132: float4-aligned, bank-safe
  __shared__ __align__(16) float sHk[16][132];
  __shared__ __align__(16) float sW2[128];

  int t = threadIdx.x;
  int row0 = blockIdx.x * 32;         // global n-row base (tile within one sb)
  int sb = row0 >> 11;                // row0 / 2048

  // stage hx tile: 32*128 floats = 1024 float4, 4 per thread, coalesced
  const float4* hx4 = (const float4*)(hx + (size_t)row0 * 128);
#pragma unroll
  for (int i = 0; i < 4; ++i) {
    int j = i * 256 + t;              // 0..1023
    int n = j >> 5, h4 = j & 31;
    *(float4*)&sHx[n][h4 * 4] = hx4[j];
  }
  // stage hk for this sb: 16*128 floats = 512 float4, 2 per thread
  const float4* hk4 = (const float4*)(hk + (size_t)sb * 2048);
#pragma unroll
  for (int i = 0; i < 2; ++i) {
    int j = i * 256 + t;              // 0..511
    int k = j >> 5, h4 = j & 31;
    *(float4*)&sHk[k][h4 * 4] = hk4[j];
  }
  if (t < 128) sW2[t] = -2.0f * W2[t];
  __syncthreads();

  int k  = t & 15;
  int nl = t >> 4;                    // 0..15; also handles nl+16
  float acc0 = 0.f, acc1 = 0.f;
#pragma unroll 4
  for (int h4 = 0; h4 < 32; ++h4) {
    float4 a0 = *(const float4*)&sHx[nl][h4 * 4];
    float4 a1 = *(const float4*)&sHx[nl + 16][h4 * 4];
    float4 b  = *(const float4*)&sHk[k][h4 * 4];
    float4 w  = *(const float4*)&sW2[h4 * 4];
    acc0 = fmaf(w.x, RCPF(1.0f + EXP2F(a0.x + b.x)), acc0);
    acc0 = fmaf(w.y, RCPF(1.0f + EXP2F(a0.y + b.y)), acc0);
    acc0 = fmaf(w.z, RCPF(1.0f + EXP2F(a0.z + b.z)), acc0);
    acc0 = fmaf(w.w, RCPF(1.0f + EXP2F(a0.w + b.w)), acc0);
    acc1 = fmaf(w.x, RCPF(1.0f + EXP2F(a1.x + b.x)), acc1);
    acc1 = fmaf(w.y, RCPF(1.0f + EXP2F(a1.y + b.y)), acc1);
    acc1 = fmaf(w.z, RCPF(1.0f + EXP2F(a1.z + b.z)), acc1);
    acc1 = fmaf(w.w, RCPF(1.0f + EXP2F(a1.w + b.w)), acc1);
  }

  // softmax over the 16 k-lanes of each group, for both n-rows
  const float l2e = 1.4426950408889634f;
  float m0 = acc0, m1 = acc1;
#pragma unroll
  for (int s = 8; s; s >>= 1) {
    m0 = fmaxf(m0, __shfl_xor(m0, s, 16));
    m1 = fmaxf(m1, __shfl_xor(m1, s, 16));
  }
  float e0 = EXP2F((acc0 - m0) * l2e);
  float e1 = EXP2F((acc1 - m1) * l2e);
  float s0 = e0, s1 = e1;
#pragma unroll
  for (int s = 8; s; s >>= 1) {
    s0 += __shfl_xor(s0, s, 16);
    s1 += __shfl_xor(s1, s, 16);
  }
  out[(size_t)(row0 + nl) * 16 + k]      = e0 * RCPF(s0);
  out[(size_t)(row0 + 16 + nl) * 16 + k] = e1 * RCPF(s1);
}

// ---------------------------------------------------------------------------
extern "C" void kernel_launch(void* const* d_in, const int* in_sizes, int n_in,
                              void* d_out, int out_size, void* d_ws, size_t ws_size,
                              hipStream_t stream) {
  const float* x   = (const float*)d_in[0];
  const float* mu  = (const float*)d_in[1];
  const float* tau = (const float*)d_in[2];
  const float* W1  = (const float*)d_in[3];
  const float* b1  = (const float*)d_in[4];
  const float* W2  = (const float*)d_in[5];
  // b2 (d_in[6]) is k-uniform -> cancelled by softmax; unused.
  float* out = (float*)d_out;

  float* hk = (float*)d_ws;            // 512*128 floats = 256 KB
  float* hx = hk + 512 * 128;          // 65536*128 floats = 32 MB
  (void)in_sizes; (void)n_in; (void)out_size; (void)ws_size;

  hk_kernel<<<256, 256, 0, stream>>>(mu, tau, W1, b1, hk);
  hx_kernel<<<512, 256, 0, stream>>>(x, W1, hx);
  main_kernel<<<2048, 256, 0, stream>>>(hx, hk, W2, out);
}

// Round 2
// 92.521 us; speedup vs baseline: 1.3008x; 1.3008x over previous
//
#include <hip/hip_runtime.h>
#include <math.h>

// Shapes: S=4 B=8 N=2048 K=16 D=32 H=128; rows SBN=65536, rows/sb=2048.
typedef _Float16 half_t;
typedef __attribute__((ext_vector_type(8))) _Float16 half8;

#define EXP2F(x) __builtin_amdgcn_exp2f(x)
#define RCPF(x)  __builtin_amdgcn_rcpf(x)
#define C_SCALE 2.8853900817779268f   // 2*log2(e): tanh(z)=1-2/(1+2^(c*z))

// ---------------------------------------------------------------------------
// prep: ek[(sb*16+k)*128+h] = f16( exp2(c*(mu@Wm + tau@Wt + b1)) )
//       w2h[h] = f16(-2*W2[h])
// ---------------------------------------------------------------------------
__global__ __launch_bounds__(256) void prep_kernel(
    const float* __restrict__ mu, const float* __restrict__ tau,
    const float* __restrict__ W1, const float* __restrict__ b1,
    const float* __restrict__ W2,
    half_t* __restrict__ ek, half_t* __restrict__ w2h) {
  int g = blockIdx.x * 256 + threadIdx.x;   // 0..65535
  int h = g & 127, row = g >> 7;            // row = sb*16+k (512 rows)
  const float* mur  = mu  + row * 32;
  const float* taur = tau + row * 32;
  float acc = b1[h];
#pragma unroll
  for (int d = 0; d < 32; ++d) {
    acc = fmaf(mur[d],  W1[(32 + d) * 128 + h], acc);   // Wm
    acc = fmaf(taur[d], W1[(64 + d) * 128 + h], acc);   // Wt
  }
  ek[g] = (half_t)EXP2F(C_SCALE * acc);
  if (g < 128) w2h[g] = (half_t)(-2.0f * W2[g]);
}

// ---------------------------------------------------------------------------
// fused main: per block, 64 n-rows of one sb.
//  phase 1: ex[r][h] = f16(exp2(c * x[r,:]@Wx[:,h]))  (LDS only)
//  phase 2: gamma[r][k] = sum_h w2h[h]*rcp(1 + ex[r][h]*ek[k][h]); softmax_k
// ---------------------------------------------------------------------------
__global__ __launch_bounds__(256, 3) void main_kernel(
    const float* __restrict__ x, const float* __restrict__ W1,
    const half_t* __restrict__ ek, const half_t* __restrict__ w2h,
    float* __restrict__ out) {
  __shared__ __align__(16) float  sX[64][36];     // x tile (pad 36: 144B rows)
  __shared__ __align__(16) float  sW[32][132];    // c*Wx (528B rows, 16B-aligned)
  __shared__ __align__(16) half_t sEx[64][136];   // f16 ex tile (272B rows)
  __shared__ __align__(16) half_t sEk[16][136];
  __shared__ __align__(16) half_t sW2[128];

  int t = threadIdx.x;
  int row0 = blockIdx.x * 64;
  int sb = row0 >> 11;

  // ---- stage x tile: 64x32 = 512 float4, coalesced ----
  const float4* x4 = (const float4*)(x + (size_t)row0 * 32);
#pragma unroll
  for (int i = 0; i < 2; ++i) {
    int j = i * 256 + t;                 // 0..511
    int n = j >> 3, d4 = j & 7;
    *(float4*)&sX[n][d4 * 4] = x4[j];
  }
  // ---- stage c*Wx: 32x128 = 1024 float4 ----
  const float4* w4 = (const float4*)W1;  // rows 0..31 are Wx
#pragma unroll
  for (int i = 0; i < 4; ++i) {
    int j = i * 256 + t;                 // 0..1023
    int d = j >> 5, h4 = j & 31;
    float4 v = w4[j];
    v.x *= C_SCALE; v.y *= C_SCALE; v.z *= C_SCALE; v.w *= C_SCALE;
    *(float4*)&sW[d][h4 * 4] = v;
  }
  // ---- stage ek (this sb): 16x128 halfs = 256 x 8-half chunks ----
  {
    const float4* ek4 = (const float4*)(ek + (size_t)sb * 2048);
    int k = t >> 4, h8 = t & 15;
    *(float4*)&sEk[k][h8 * 8] = ek4[t];
  }
  if (t < 16) *(float4*)&sW2[t * 8] = ((const float4*)w2h)[t];
  __syncthreads();

  // ---- phase 1: hx GEMM -> exp2 -> f16 LDS tile ----
  {
    int hg = t & 15, rg = t >> 4;        // 16 h-octs x 16 row-quads
    int h0 = hg * 8, r0 = rg * 4;
    float acc[4][8];
#pragma unroll
    for (int j = 0; j < 4; ++j)
#pragma unroll
      for (int l = 0; l < 8; ++l) acc[j][l] = 0.f;
#pragma unroll 4
    for (int d = 0; d < 32; ++d) {
      float4 wa = *(const float4*)&sW[d][h0];
      float4 wb = *(const float4*)&sW[d][h0 + 4];
      float w[8] = {wa.x, wa.y, wa.z, wa.w, wb.x, wb.y, wb.z, wb.w};
#pragma unroll
      for (int j = 0; j < 4; ++j) {
        float xv = sX[r0 + j][d];        // broadcast among 16 lanes
#pragma unroll
        for (int l = 0; l < 8; ++l) acc[j][l] = fmaf(xv, w[l], acc[j][l]);
      }
    }
#pragma unroll
    for (int j = 0; j < 4; ++j) {
      half8 hv;
#pragma unroll
      for (int l = 0; l < 8; ++l) hv[l] = (half_t)EXP2F(acc[j][l]);
      *(half8*)&sEx[r0 + j][h0] = hv;
    }
  }
  __syncthreads();

  // ---- phase 2: hot loop, 2 rows x 2 k per thread ----
  int kg = t & 7, rg = t >> 3;           // rg 0..31
  int r0 = rg * 2, k0 = kg * 2;
  float a00 = 0.f, a01 = 0.f, a10 = 0.f, a11 = 0.f;
#pragma unroll 2
  for (int h8 = 0; h8 < 16; ++h8) {
    half8 ex0 = *(const half8*)&sEx[r0][h8 * 8];
    half8 ex1 = *(const half8*)&sEx[r0 + 1][h8 * 8];
    half8 ekv0 = *(const half8*)&sEk[k0][h8 * 8];
    half8 ekv1 = *(const half8*)&sEk[k0 + 1][h8 * 8];
    half8 wv = *(const half8*)&sW2[h8 * 8];
#pragma unroll
    for (int j = 0; j < 8; ++j) {
      float e0 = (float)ex0[j], e1 = (float)ex1[j];
      float f0 = (float)ekv0[j], f1 = (float)ekv1[j];
      float w = (float)wv[j];
      a00 = fmaf(w, RCPF(fmaf(e0, f0, 1.0f)), a00);
      a01 = fmaf(w, RCPF(fmaf(e0, f1, 1.0f)), a01);
      a10 = fmaf(w, RCPF(fmaf(e1, f0, 1.0f)), a10);
      a11 = fmaf(w, RCPF(fmaf(e1, f1, 1.0f)), a11);
    }
  }

  // ---- softmax over k: 2 k in-thread x 8 kg-lanes (shuffle width 8) ----
  const float l2e = 1.4426950408889634f;
  {
    float m = fmaxf(a00, a01);
#pragma unroll
    for (int s = 1; s < 8; s <<= 1) m = fmaxf(m, __shfl_xor(m, s, 8));
    float p0 = EXP2F((a00 - m) * l2e), p1 = EXP2F((a01 - m) * l2e);
    float sum = p0 + p1;
#pragma unroll
    for (int s = 1; s < 8; s <<= 1) sum += __shfl_xor(sum, s, 8);
    float inv = RCPF(sum);
    float2 o = make_float2(p0 * inv, p1 * inv);
    *(float2*)&out[(size_t)(row0 + r0) * 16 + k0] = o;
  }
  {
    float m = fmaxf(a10, a11);
#pragma unroll
    for (int s = 1; s < 8; s <<= 1) m = fmaxf(m, __shfl_xor(m, s, 8));
    float p0 = EXP2F((a10 - m) * l2e), p1 = EXP2F((a11 - m) * l2e);
    float sum = p0 + p1;
#pragma unroll
    for (int s = 1; s < 8; s <<= 1) sum += __shfl_xor(sum, s, 8);
    float inv = RCPF(sum);
    float2 o = make_float2(p0 * inv, p1 * inv);
    *(float2*)&out[(size_t)(row0 + r0 + 1) * 16 + k0] = o;
  }
}

// ---------------------------------------------------------------------------
extern "C" void kernel_launch(void* const* d_in, const int* in_sizes, int n_in,
                              void* d_out, int out_size, void* d_ws, size_t ws_size,
                              hipStream_t stream) {
  const float* x   = (const float*)d_in[0];
  const float* mu  = (const float*)d_in[1];
  const float* tau = (const float*)d_in[2];
  const float* W1  = (const float*)d_in[3];
  const float* b1  = (const float*)d_in[4];
  const float* W2  = (const float*)d_in[5];
  // b2 (d_in[6]) and sum(W2) are k-uniform -> cancelled by softmax.
  float* out = (float*)d_out;

  half_t* ek  = (half_t*)d_ws;           // 512*128 halfs = 128 KB
  half_t* w2h = ek + 512 * 128;          // 128 halfs
  (void)in_sizes; (void)n_in; (void)out_size; (void)ws_size;

  prep_kernel<<<256, 256, 0, stream>>>(mu, tau, W1, b1, W2, ek, w2h);
  main_kernel<<<1024, 256, 0, stream>>>(x, W1, ek, w2h, out);
}